// Round 1
// baseline (1579.302 us; speedup 1.0000x reference)
//
#include <hip/hip_runtime.h>
#include <math.h>

#define S_LEN 2048
#define NH 16
#define DK 64
#define DM 1024
#define BB 2
#define NROWS (BB * S_LEN)   // 4096
#define BHN (BB * NH)        // 32

// ===================================================================
// Projection / output GEMM:  C = A(M x 1024) @ W(1024 x 1024)^T + bias
// A row-major, W row-major (torch Linear layout -> NT GEMM, both read
// along K contiguously). 128x128 tile, BK=32, 256 threads, 8x8 micro.
// OUT_MODE 0: C row-major (M x 1024)        [out projection]
// OUT_MODE 1: C in (B, H, S, DK) layout     [q/k/v projections]
// ===================================================================
template<int OUT_MODE>
__global__ __launch_bounds__(256)
void gemm_xwt(const float* __restrict__ A, const float* __restrict__ W,
              const float* __restrict__ bias, float* __restrict__ C)
{
  constexpr int LDT = 132;            // 128 + 4 pad, float4-aligned stride
  __shared__ float As[32 * LDT];      // k-major [k][m]
  __shared__ float Bs[32 * LDT];      // k-major [k][n]
  const int tid = threadIdx.x;
  const int tx = tid & 15, ty = tid >> 4;
  const int m0 = blockIdx.y * 128, n0 = blockIdx.x * 128;

  float acc[8][8];
  #pragma unroll
  for (int i = 0; i < 8; ++i)
    #pragma unroll
    for (int j = 0; j < 8; ++j) acc[i][j] = 0.f;

  for (int k0 = 0; k0 < 1024; k0 += 32) {
    // stage A and W tiles (128 rows x 32 k), transpose into k-major LDS
    #pragma unroll
    for (int i = 0; i < 4; ++i) {
      const int f = tid + i * 256;     // 0..1023
      const int m = f >> 3;            // 0..127
      const int kq = (f & 7) * 4;      // 0..28
      const float4 av = *(const float4*)(A + (size_t)(m0 + m) * 1024 + k0 + kq);
      As[(kq + 0) * LDT + m] = av.x;
      As[(kq + 1) * LDT + m] = av.y;
      As[(kq + 2) * LDT + m] = av.z;
      As[(kq + 3) * LDT + m] = av.w;
      const float4 wv = *(const float4*)(W + (size_t)(n0 + m) * 1024 + k0 + kq);
      Bs[(kq + 0) * LDT + m] = wv.x;
      Bs[(kq + 1) * LDT + m] = wv.y;
      Bs[(kq + 2) * LDT + m] = wv.z;
      Bs[(kq + 3) * LDT + m] = wv.w;
    }
    __syncthreads();
    #pragma unroll
    for (int kk = 0; kk < 32; ++kk) {
      const float4 a0 = *(const float4*)(As + kk * LDT + ty * 8);
      const float4 a1 = *(const float4*)(As + kk * LDT + ty * 8 + 4);
      const float4 b0 = *(const float4*)(Bs + kk * LDT + tx * 8);
      const float4 b1 = *(const float4*)(Bs + kk * LDT + tx * 8 + 4);
      const float av[8] = {a0.x, a0.y, a0.z, a0.w, a1.x, a1.y, a1.z, a1.w};
      const float bv[8] = {b0.x, b0.y, b0.z, b0.w, b1.x, b1.y, b1.z, b1.w};
      #pragma unroll
      for (int i = 0; i < 8; ++i)
        #pragma unroll
        for (int j = 0; j < 8; ++j)
          acc[i][j] = fmaf(av[i], bv[j], acc[i][j]);
    }
    __syncthreads();
  }

  #pragma unroll
  for (int i = 0; i < 8; ++i) {
    const int m = m0 + ty * 8 + i;
    #pragma unroll
    for (int j4 = 0; j4 < 2; ++j4) {
      const int n = n0 + tx * 8 + j4 * 4;
      const float4 bb = *(const float4*)(bias + n);
      float4 o;
      o.x = acc[i][j4 * 4 + 0] + bb.x;
      o.y = acc[i][j4 * 4 + 1] + bb.y;
      o.z = acc[i][j4 * 4 + 2] + bb.z;
      o.w = acc[i][j4 * 4 + 3] + bb.w;
      if (OUT_MODE == 0) {
        *(float4*)(C + (size_t)m * 1024 + n) = o;
      } else {
        const int b = m >> 11, s = m & (S_LEN - 1);
        const int h = n >> 6, d = n & 63;
        *(float4*)(C + (((size_t)(b * NH + h) * S_LEN + s) * DK + d)) = o;
      }
    }
  }
}

// ===================================================================
// Scores: attn_raw[bh, q, k] = (Q[bh,q,:] . K[bh,k,:]) / 8
// Only lower-triangular 128x128 blocks (kb <= qb). Upper area is left
// untouched (softmax ignores it). 128x128 tile, K=64 in two BK=32 steps.
// grid: x = triangular block index (136), y = bh (32)
// ===================================================================
__global__ __launch_bounds__(256)
void scores_kernel(const float* __restrict__ Qp, const float* __restrict__ Kp,
                   float* __restrict__ attn)
{
  constexpr int LDT = 132;
  __shared__ float Qs[32 * LDT];
  __shared__ float Ks[32 * LDT];
  const int tid = threadIdx.x;
  const int tx = tid & 15, ty = tid >> 4;
  const int bh = blockIdx.y;
  const int r = blockIdx.x;
  int qb = 0;
  while ((qb + 1) * (qb + 2) / 2 <= r) qb++;
  const int kb = r - qb * (qb + 1) / 2;
  const int q0 = qb * 128, kcol0 = kb * 128;
  const float* Qb = Qp + ((size_t)bh * S_LEN + q0) * DK;
  const float* Kb = Kp + ((size_t)bh * S_LEN + kcol0) * DK;

  float acc[8][8];
  #pragma unroll
  for (int i = 0; i < 8; ++i)
    #pragma unroll
    for (int j = 0; j < 8; ++j) acc[i][j] = 0.f;

  for (int k0 = 0; k0 < DK; k0 += 32) {
    #pragma unroll
    for (int i = 0; i < 4; ++i) {
      const int f = tid + i * 256;
      const int m = f >> 3;
      const int kq = (f & 7) * 4;
      const float4 av = *(const float4*)(Qb + (size_t)m * DK + k0 + kq);
      Qs[(kq + 0) * LDT + m] = av.x;
      Qs[(kq + 1) * LDT + m] = av.y;
      Qs[(kq + 2) * LDT + m] = av.z;
      Qs[(kq + 3) * LDT + m] = av.w;
      const float4 bv = *(const float4*)(Kb + (size_t)m * DK + k0 + kq);
      Ks[(kq + 0) * LDT + m] = bv.x;
      Ks[(kq + 1) * LDT + m] = bv.y;
      Ks[(kq + 2) * LDT + m] = bv.z;
      Ks[(kq + 3) * LDT + m] = bv.w;
    }
    __syncthreads();
    #pragma unroll
    for (int kk = 0; kk < 32; ++kk) {
      const float4 a0 = *(const float4*)(Qs + kk * LDT + ty * 8);
      const float4 a1 = *(const float4*)(Qs + kk * LDT + ty * 8 + 4);
      const float4 b0 = *(const float4*)(Ks + kk * LDT + tx * 8);
      const float4 b1 = *(const float4*)(Ks + kk * LDT + tx * 8 + 4);
      const float av[8] = {a0.x, a0.y, a0.z, a0.w, a1.x, a1.y, a1.z, a1.w};
      const float bv[8] = {b0.x, b0.y, b0.z, b0.w, b1.x, b1.y, b1.z, b1.w};
      #pragma unroll
      for (int i = 0; i < 8; ++i)
        #pragma unroll
        for (int j = 0; j < 8; ++j)
          acc[i][j] = fmaf(av[i], bv[j], acc[i][j]);
    }
    __syncthreads();
  }

  #pragma unroll
  for (int i = 0; i < 8; ++i) {
    const int qi = q0 + ty * 8 + i;
    float* orow = attn + ((size_t)bh * S_LEN + qi) * S_LEN + kcol0 + tx * 8;
    float4 o0, o1;
    o0.x = acc[i][0] * 0.125f; o0.y = acc[i][1] * 0.125f;
    o0.z = acc[i][2] * 0.125f; o0.w = acc[i][3] * 0.125f;
    o1.x = acc[i][4] * 0.125f; o1.y = acc[i][5] * 0.125f;
    o1.z = acc[i][6] * 0.125f; o1.w = acc[i][7] * 0.125f;
    *(float4*)(orow) = o0;
    *(float4*)(orow + 4) = o1;
  }
}

// ===================================================================
// Row softmax over attn, in place. One 256-thread block per row.
// Reads only k <= q (masked region is never read); writes the FULL row
// (zeros for k > q) -> implements the causal mask exactly.
// ===================================================================
__global__ __launch_bounds__(256)
void softmax_kernel(float* __restrict__ attn)
{
  const int row = blockIdx.x;            // 0 .. B*H*S-1
  const int q = row & (S_LEN - 1);
  float* rowp = attn + (size_t)row * S_LEN;
  const int t = threadIdx.x;

  float vals[8];
  float m = -INFINITY;
  #pragma unroll
  for (int i = 0; i < 2; ++i) {
    const int c0 = (i * 256 + t) * 4;
    float4 x = make_float4(-INFINITY, -INFINITY, -INFINITY, -INFINITY);
    if (c0 <= q) x = *(const float4*)(rowp + c0);
    vals[i * 4 + 0] = (c0 + 0 <= q) ? x.x : -INFINITY;
    vals[i * 4 + 1] = (c0 + 1 <= q) ? x.y : -INFINITY;
    vals[i * 4 + 2] = (c0 + 2 <= q) ? x.z : -INFINITY;
    vals[i * 4 + 3] = (c0 + 3 <= q) ? x.w : -INFINITY;
    m = fmaxf(m, fmaxf(fmaxf(vals[i*4], vals[i*4+1]), fmaxf(vals[i*4+2], vals[i*4+3])));
  }
  #pragma unroll
  for (int off = 32; off > 0; off >>= 1)
    m = fmaxf(m, __shfl_xor(m, off));
  __shared__ float red[8];
  if ((t & 63) == 0) red[t >> 6] = m;
  __syncthreads();
  m = fmaxf(fmaxf(red[0], red[1]), fmaxf(red[2], red[3]));

  float s = 0.f;
  #pragma unroll
  for (int i = 0; i < 8; ++i) {
    const float e = __expf(vals[i] - m);   // exp(-inf - m) = 0 for masked
    vals[i] = e;
    s += e;
  }
  #pragma unroll
  for (int off = 32; off > 0; off >>= 1)
    s += __shfl_xor(s, off);
  if ((t & 63) == 0) red[4 + (t >> 6)] = s;   // disjoint slots, no extra sync needed
  __syncthreads();
  s = (red[4] + red[5]) + (red[6] + red[7]);
  const float inv = 1.0f / s;

  #pragma unroll
  for (int i = 0; i < 2; ++i) {
    const int c0 = (i * 256 + t) * 4;
    float4 o;
    o.x = vals[i * 4 + 0] * inv;
    o.y = vals[i * 4 + 1] * inv;
    o.z = vals[i * 4 + 2] * inv;
    o.w = vals[i * 4 + 3] * inv;
    *(float4*)(rowp + c0) = o;             // masked entries are exact 0
  }
}

// ===================================================================
// PV: ctx[b, q, h*64+d] = sum_{k<=q} attn[bh,q,k] * V[bh,k,d]
// attn zeros above the diagonal make the diagonal block exact.
// 128(q) x 64(d) tile, BK=32, 256 threads, 8x4 micro.
// grid: x = qb (16, launched largest-first), y = bh (32)
// ===================================================================
__global__ __launch_bounds__(256)
void pv_kernel(const float* __restrict__ attn, const float* __restrict__ Vp,
               float* __restrict__ ctx)
{
  constexpr int LDA = 132, LDB = 68;
  __shared__ float As[32 * LDA];
  __shared__ float Bs[32 * LDB];
  const int tid = threadIdx.x;
  const int tx = tid & 15, ty = tid >> 4;
  const int bh = blockIdx.y;
  const int qb = 15 - blockIdx.x;        // biggest blocks first
  const int q0 = qb * 128;
  const float* Arow = attn + ((size_t)bh * S_LEN + q0) * S_LEN;
  const float* Vb = Vp + (size_t)bh * S_LEN * DK;

  float acc[8][4];
  #pragma unroll
  for (int i = 0; i < 8; ++i)
    #pragma unroll
    for (int j = 0; j < 4; ++j) acc[i][j] = 0.f;

  const int nk = (q0 + 128) / 32;
  for (int kt = 0; kt < nk; ++kt) {
    const int k0 = kt * 32;
    #pragma unroll
    for (int i = 0; i < 4; ++i) {        // stage attn chunk (128 x 32), transpose
      const int f = tid + i * 256;
      const int m = f >> 3;
      const int kq = (f & 7) * 4;
      const float4 av = *(const float4*)(Arow + (size_t)m * S_LEN + k0 + kq);
      As[(kq + 0) * LDA + m] = av.x;
      As[(kq + 1) * LDA + m] = av.y;
      As[(kq + 2) * LDA + m] = av.z;
      As[(kq + 3) * LDA + m] = av.w;
    }
    #pragma unroll
    for (int i = 0; i < 2; ++i) {        // stage V chunk (32 x 64), natural
      const int f = tid + i * 256;
      const int kk = f >> 4;
      const int dq = (f & 15) * 4;
      *(float4*)(Bs + kk * LDB + dq) =
          *(const float4*)(Vb + (size_t)(k0 + kk) * DK + dq);
    }
    __syncthreads();
    #pragma unroll
    for (int kk = 0; kk < 32; ++kk) {
      const float4 a0 = *(const float4*)(As + kk * LDA + ty * 8);
      const float4 a1 = *(const float4*)(As + kk * LDA + ty * 8 + 4);
      const float4 b  = *(const float4*)(Bs + kk * LDB + tx * 4);
      const float av[8] = {a0.x, a0.y, a0.z, a0.w, a1.x, a1.y, a1.z, a1.w};
      const float bv[4] = {b.x, b.y, b.z, b.w};
      #pragma unroll
      for (int i = 0; i < 8; ++i)
        #pragma unroll
        for (int j = 0; j < 4; ++j)
          acc[i][j] = fmaf(av[i], bv[j], acc[i][j]);
    }
    __syncthreads();
  }

  const int b = bh >> 4, h = bh & 15;
  #pragma unroll
  for (int i = 0; i < 8; ++i) {
    const int sIdx = q0 + ty * 8 + i;
    float4 o;
    o.x = acc[i][0]; o.y = acc[i][1]; o.z = acc[i][2]; o.w = acc[i][3];
    *(float4*)(ctx + ((size_t)b * S_LEN + sIdx) * DM + h * DK + tx * 4) = o;
  }
}

// ===================================================================
extern "C" void kernel_launch(void* const* d_in, const int* in_sizes, int n_in,
                              void* d_out, int out_size, void* d_ws, size_t ws_size,
                              hipStream_t stream) {
  const float* q   = (const float*)d_in[0];
  const float* k   = (const float*)d_in[1];
  const float* v   = (const float*)d_in[2];
  // d_in[3] = causal mask -> implemented analytically, never read
  const float* w_q = (const float*)d_in[4];
  const float* b_q = (const float*)d_in[5];
  const float* w_k = (const float*)d_in[6];
  const float* b_k = (const float*)d_in[7];
  const float* w_v = (const float*)d_in[8];
  const float* b_v = (const float*)d_in[9];
  const float* w_o = (const float*)d_in[10];
  const float* b_o = (const float*)d_in[11];

  float* out  = (float*)d_out;                       // (B, S, DM)
  float* attn = out + (size_t)NROWS * DM;            // (B, H, S, S)

  float* ws  = (float*)d_ws;                         // needs 64 MiB
  float* Qp  = ws;                                   // (B, H, S, DK)
  float* Kp  = ws + (size_t)NROWS * DM;
  float* Vp  = ws + 2 * (size_t)NROWS * DM;
  float* ctx = ws + 3 * (size_t)NROWS * DM;          // (B, S, DM)

  const dim3 gproj(DM / 128, NROWS / 128);           // (8, 32)
  gemm_xwt<1><<<gproj, 256, 0, stream>>>(q, w_q, b_q, Qp);
  gemm_xwt<1><<<gproj, 256, 0, stream>>>(k, w_k, b_k, Kp);
  gemm_xwt<1><<<gproj, 256, 0, stream>>>(v, w_v, b_v, Vp);

  scores_kernel<<<dim3(136, BHN), 256, 0, stream>>>(Qp, Kp, attn);
  softmax_kernel<<<dim3(BB * NH * S_LEN), 256, 0, stream>>>(attn);
  pv_kernel<<<dim3(16, BHN), 256, 0, stream>>>(attn, Vp, ctx);

  gemm_xwt<0><<<gproj, 256, 0, stream>>>(ctx, w_o, b_o, out);
}

// Round 2
// 1262.464 us; speedup vs baseline: 1.2510x; 1.2510x over previous
//
#include <hip/hip_runtime.h>
#include <hip/hip_bf16.h>
#include <math.h>

#define S_LEN 2048
#define NH 16
#define DK 64
#define DM 1024
#define BB 2
#define NROWS (BB * S_LEN)   // 4096
#define BHN (BB * NH)        // 32

typedef __attribute__((ext_vector_type(8))) short short8;          // MFMA A/B frag (8 bf16)
typedef __attribute__((ext_vector_type(8))) unsigned short u16x8;  // LDS store vector
typedef __attribute__((ext_vector_type(4))) float f32x4;           // MFMA C/D frag

#define LDS_W 72   // ushorts per LDS row: 64 data + 8 pad = 144B (stride 9 x 16B slots)

__device__ __forceinline__ unsigned short f2bf(float x) {
  return __builtin_bit_cast(unsigned short, __float2bfloat16(x));  // RNE
}
__device__ __forceinline__ float bf2f(unsigned short u) {
  return __uint_as_float(((unsigned)u) << 16);
}

// Stage a 128x64 fp32 tile (row stride ld) into hi/lo bf16 LDS planes.
__device__ __forceinline__ void stage128x64(const float* __restrict__ base, int ld,
                                            unsigned short* sh, unsigned short* sl,
                                            int tid) {
  #pragma unroll
  for (int i = 0; i < 4; ++i) {
    const int f = tid + i * 256;        // 0..1023
    const int r = f >> 3;               // 0..127
    const int c = (f & 7) * 8;          // 0..56
    const float* p = base + (size_t)r * ld + c;
    const float4 v0 = *(const float4*)(p);
    const float4 v1 = *(const float4*)(p + 4);
    const float xs[8] = {v0.x, v0.y, v0.z, v0.w, v1.x, v1.y, v1.z, v1.w};
    u16x8 hv, lv;
    #pragma unroll
    for (int j = 0; j < 8; ++j) {
      const unsigned short h = f2bf(xs[j]);
      hv[j] = h;
      lv[j] = f2bf(xs[j] - bf2f(h));
    }
    *(u16x8*)(sh + r * LDS_W + c) = hv;
    *(u16x8*)(sl + r * LDS_W + c) = lv;
  }
}

// ===================================================================
// Unified NT MFMA GEMM, 128x128 tile, BK=64, 256 threads (4 waves 2x2),
// split-bf16 3-pass (Ah*Bh + Al*Bh + Ah*Bl), fp32 accumulate.
// MODE 0: C = A @ W^T + bias, fp32 row-major (out projection)
// MODE 1: same math, C written in (B,H,S,DK) fp32 layout (q/k/v proj)
// MODE 2: scores = (Qp @ Kp^T)/8 per bh, lower-triangular blocks only
// ===================================================================
template<int MODE>
__global__ __launch_bounds__(256)
void mfma_gemm(const float* __restrict__ A, const float* __restrict__ Bm,
               const float* __restrict__ bias, float* __restrict__ C)
{
  __shared__ unsigned short As_h[128 * LDS_W], As_l[128 * LDS_W];
  __shared__ unsigned short Bs_h[128 * LDS_W], Bs_l[128 * LDS_W];
  const int tid = threadIdx.x;
  const int lane = tid & 63, wv = tid >> 6;
  const int wr = wv >> 1, wc = wv & 1;
  const int lr = lane & 15, lg = lane >> 4;

  int m0, n0, lda, ldb, kiters;
  const float *Ab, *Bb;
  if (MODE == 2) {
    const int r = blockIdx.x;
    int qb = 0;
    while ((qb + 1) * (qb + 2) / 2 <= r) qb++;
    const int kb = r - qb * (qb + 1) / 2;
    m0 = qb * 128; n0 = kb * 128;
    Ab = A  + ((size_t)blockIdx.y * S_LEN + m0) * DK;
    Bb = Bm + ((size_t)blockIdx.y * S_LEN + n0) * DK;
    lda = DK; ldb = DK; kiters = 1;
  } else {
    m0 = blockIdx.y * 128; n0 = blockIdx.x * 128;
    Ab = A  + (size_t)m0 * DM;
    Bb = Bm + (size_t)n0 * DM;
    lda = DM; ldb = DM; kiters = DM / 64;
  }

  f32x4 acc[4][4];
  #pragma unroll
  for (int m = 0; m < 4; ++m)
    #pragma unroll
    for (int n = 0; n < 4; ++n) acc[m][n] = (f32x4){0.f, 0.f, 0.f, 0.f};

  for (int kt = 0; kt < kiters; ++kt) {
    stage128x64(Ab + kt * 64, lda, As_h, As_l, tid);
    stage128x64(Bb + kt * 64, ldb, Bs_h, Bs_l, tid);
    __syncthreads();
    #pragma unroll
    for (int kk = 0; kk < 2; ++kk) {
      short8 ah[4], al[4], bh2[4], bl2[4];
      #pragma unroll
      for (int m = 0; m < 4; ++m) {
        const int off = (wr * 64 + m * 16 + lr) * LDS_W + kk * 32 + lg * 8;
        ah[m] = *(const short8*)(As_h + off);
        al[m] = *(const short8*)(As_l + off);
      }
      #pragma unroll
      for (int n = 0; n < 4; ++n) {
        const int off = (wc * 64 + n * 16 + lr) * LDS_W + kk * 32 + lg * 8;
        bh2[n] = *(const short8*)(Bs_h + off);
        bl2[n] = *(const short8*)(Bs_l + off);
      }
      #pragma unroll
      for (int m = 0; m < 4; ++m)
        #pragma unroll
        for (int n = 0; n < 4; ++n) {
          acc[m][n] = __builtin_amdgcn_mfma_f32_16x16x32_bf16(ah[m], bh2[n], acc[m][n], 0, 0, 0);
          acc[m][n] = __builtin_amdgcn_mfma_f32_16x16x32_bf16(al[m], bh2[n], acc[m][n], 0, 0, 0);
          acc[m][n] = __builtin_amdgcn_mfma_f32_16x16x32_bf16(ah[m], bl2[n], acc[m][n], 0, 0, 0);
        }
    }
    __syncthreads();
  }

  // epilogue: C layout col = lane&15, row = (lane>>4)*4 + j (verified m89)
  #pragma unroll
  for (int n = 0; n < 4; ++n) {
    const int col = n0 + wc * 64 + n * 16 + lr;
    const float bb = (MODE == 2) ? 0.f : bias[col];
    #pragma unroll
    for (int m = 0; m < 4; ++m) {
      const int rbase = m0 + wr * 64 + m * 16 + lg * 4;
      #pragma unroll
      for (int j = 0; j < 4; ++j) {
        const int row = rbase + j;
        const float o = acc[m][n][j];
        if (MODE == 2) {
          C[((size_t)blockIdx.y * S_LEN + row) * S_LEN + col] = o * 0.125f;
        } else if (MODE == 0) {
          C[(size_t)row * DM + col] = o + bb;
        } else {
          const int b = row >> 11, s = row & (S_LEN - 1);
          const int h = col >> 6, d = col & 63;
          C[(((size_t)(b * NH + h) * S_LEN + s) * DK + d)] = o + bb;
        }
      }
    }
  }
}

// ===================================================================
// Row softmax over attn, in place (unchanged from round 0).
// ===================================================================
__global__ __launch_bounds__(256)
void softmax_kernel(float* __restrict__ attn)
{
  const int row = blockIdx.x;
  const int q = row & (S_LEN - 1);
  float* rowp = attn + (size_t)row * S_LEN;
  const int t = threadIdx.x;

  float vals[8];
  float m = -INFINITY;
  #pragma unroll
  for (int i = 0; i < 2; ++i) {
    const int c0 = (i * 256 + t) * 4;
    float4 x = make_float4(-INFINITY, -INFINITY, -INFINITY, -INFINITY);
    if (c0 <= q) x = *(const float4*)(rowp + c0);
    vals[i * 4 + 0] = (c0 + 0 <= q) ? x.x : -INFINITY;
    vals[i * 4 + 1] = (c0 + 1 <= q) ? x.y : -INFINITY;
    vals[i * 4 + 2] = (c0 + 2 <= q) ? x.z : -INFINITY;
    vals[i * 4 + 3] = (c0 + 3 <= q) ? x.w : -INFINITY;
    m = fmaxf(m, fmaxf(fmaxf(vals[i*4], vals[i*4+1]), fmaxf(vals[i*4+2], vals[i*4+3])));
  }
  #pragma unroll
  for (int off = 32; off > 0; off >>= 1)
    m = fmaxf(m, __shfl_xor(m, off));
  __shared__ float red[8];
  if ((t & 63) == 0) red[t >> 6] = m;
  __syncthreads();
  m = fmaxf(fmaxf(red[0], red[1]), fmaxf(red[2], red[3]));

  float s = 0.f;
  #pragma unroll
  for (int i = 0; i < 8; ++i) {
    const float e = __expf(vals[i] - m);
    vals[i] = e;
    s += e;
  }
  #pragma unroll
  for (int off = 32; off > 0; off >>= 1)
    s += __shfl_xor(s, off);
  if ((t & 63) == 0) red[4 + (t >> 6)] = s;
  __syncthreads();
  s = (red[4] + red[5]) + (red[6] + red[7]);
  const float inv = 1.0f / s;

  #pragma unroll
  for (int i = 0; i < 2; ++i) {
    const int c0 = (i * 256 + t) * 4;
    float4 o;
    o.x = vals[i * 4 + 0] * inv;
    o.y = vals[i * 4 + 1] * inv;
    o.z = vals[i * 4 + 2] * inv;
    o.w = vals[i * 4 + 3] * inv;
    *(float4*)(rowp + c0) = o;
  }
}

// ===================================================================
// PV: ctx[b,s,h*64+d] = sum_{k<=q} attn[bh,q,k] * V[bh,k,d]
// 128(q) x 64(d) tile, BK=64, NN GEMM via transposed V staging.
// 4 waves, each 32 q-rows x 64 cols: acc[2][4]. Split-bf16 3-pass.
// ===================================================================
__global__ __launch_bounds__(256)
void pv_mfma(const float* __restrict__ attn, const float* __restrict__ Vp,
             float* __restrict__ ctx)
{
  __shared__ unsigned short As_h[128 * LDS_W], As_l[128 * LDS_W];
  __shared__ unsigned short Vs_h[64 * LDS_W],  Vs_l[64 * LDS_W];
  const int tid = threadIdx.x;
  const int lane = tid & 63, wv = tid >> 6;
  const int lr = lane & 15, lg = lane >> 4;
  const int bh = blockIdx.y;
  const int qb = 15 - blockIdx.x;           // biggest k-ranges first
  const int q0 = qb * 128;
  const float* Ab = attn + ((size_t)bh * S_LEN + q0) * S_LEN;
  const float* Vb = Vp + (size_t)bh * S_LEN * DK;

  f32x4 acc[2][4];
  #pragma unroll
  for (int m = 0; m < 2; ++m)
    #pragma unroll
    for (int n = 0; n < 4; ++n) acc[m][n] = (f32x4){0.f, 0.f, 0.f, 0.f};

  const int nk = (q0 + 128) / 64;
  for (int kt = 0; kt < nk; ++kt) {
    stage128x64(Ab + kt * 64, S_LEN, As_h, As_l, tid);
    // stage V 64x64, transposed into Vs[n][k] hi/lo
    #pragma unroll
    for (int i = 0; i < 4; ++i) {
      const int g = tid + i * 256;          // 0..1023
      const int kr = g >> 4;                // 0..63
      const int c4 = (g & 15) * 4;          // 0..60
      const float4 v = *(const float4*)(Vb + (size_t)(kt * 64 + kr) * DK + c4);
      const float xs[4] = {v.x, v.y, v.z, v.w};
      #pragma unroll
      for (int j = 0; j < 4; ++j) {
        const unsigned short h = f2bf(xs[j]);
        Vs_h[(c4 + j) * LDS_W + kr] = h;
        Vs_l[(c4 + j) * LDS_W + kr] = f2bf(xs[j] - bf2f(h));
      }
    }
    __syncthreads();
    #pragma unroll
    for (int kk = 0; kk < 2; ++kk) {
      short8 ah[2], al[2], bh2[4], bl2[4];
      #pragma unroll
      for (int m = 0; m < 2; ++m) {
        const int off = (wv * 32 + m * 16 + lr) * LDS_W + kk * 32 + lg * 8;
        ah[m] = *(const short8*)(As_h + off);
        al[m] = *(const short8*)(As_l + off);
      }
      #pragma unroll
      for (int n = 0; n < 4; ++n) {
        const int off = (n * 16 + lr) * LDS_W + kk * 32 + lg * 8;
        bh2[n] = *(const short8*)(Vs_h + off);
        bl2[n] = *(const short8*)(Vs_l + off);
      }
      #pragma unroll
      for (int m = 0; m < 2; ++m)
        #pragma unroll
        for (int n = 0; n < 4; ++n) {
          acc[m][n] = __builtin_amdgcn_mfma_f32_16x16x32_bf16(ah[m], bh2[n], acc[m][n], 0, 0, 0);
          acc[m][n] = __builtin_amdgcn_mfma_f32_16x16x32_bf16(al[m], bh2[n], acc[m][n], 0, 0, 0);
          acc[m][n] = __builtin_amdgcn_mfma_f32_16x16x32_bf16(ah[m], bl2[n], acc[m][n], 0, 0, 0);
        }
    }
    __syncthreads();
  }

  const int b = bh >> 4, h = bh & 15;
  #pragma unroll
  for (int n = 0; n < 4; ++n) {
    const int d = n * 16 + lr;
    #pragma unroll
    for (int m = 0; m < 2; ++m) {
      #pragma unroll
      for (int j = 0; j < 4; ++j) {
        const int s = q0 + wv * 32 + m * 16 + lg * 4 + j;
        ctx[((size_t)b * S_LEN + s) * DM + h * DK + d] = acc[m][n][j];
      }
    }
  }
}

// ===================================================================
extern "C" void kernel_launch(void* const* d_in, const int* in_sizes, int n_in,
                              void* d_out, int out_size, void* d_ws, size_t ws_size,
                              hipStream_t stream) {
  const float* q   = (const float*)d_in[0];
  const float* k   = (const float*)d_in[1];
  const float* v   = (const float*)d_in[2];
  // d_in[3] = causal mask -> analytic, never read
  const float* w_q = (const float*)d_in[4];
  const float* b_q = (const float*)d_in[5];
  const float* w_k = (const float*)d_in[6];
  const float* b_k = (const float*)d_in[7];
  const float* w_v = (const float*)d_in[8];
  const float* b_v = (const float*)d_in[9];
  const float* w_o = (const float*)d_in[10];
  const float* b_o = (const float*)d_in[11];

  float* out  = (float*)d_out;                      // (B, S, DM)
  float* attn = out + (size_t)NROWS * DM;           // (B, H, S, S)

  float* ws  = (float*)d_ws;                        // 64 MiB
  float* Qp  = ws;                                  // (B, H, S, DK)
  float* Kp  = ws + (size_t)NROWS * DM;
  float* Vp  = ws + 2 * (size_t)NROWS * DM;
  float* ctx = ws + 3 * (size_t)NROWS * DM;         // (B, S, DM)

  const dim3 gproj(DM / 128, NROWS / 128);          // (8, 32)
  mfma_gemm<1><<<gproj, 256, 0, stream>>>(q, w_q, b_q, Qp);
  mfma_gemm<1><<<gproj, 256, 0, stream>>>(k, w_k, b_k, Kp);
  mfma_gemm<1><<<gproj, 256, 0, stream>>>(v, w_v, b_v, Vp);

  mfma_gemm<2><<<dim3(136, BHN), 256, 0, stream>>>(Qp, Kp, nullptr, attn);
  softmax_kernel<<<dim3(BB * NH * S_LEN), 256, 0, stream>>>(attn);
  pv_mfma<<<dim3(16, BHN), 256, 0, stream>>>(attn, Vp, ctx);

  mfma_gemm<0><<<gproj, 256, 0, stream>>>(ctx, w_o, b_o, out);
}

// Round 3
// 1053.047 us; speedup vs baseline: 1.4997x; 1.1989x over previous
//
#include <hip/hip_runtime.h>
#include <hip/hip_bf16.h>
#include <math.h>

#define S_LEN 2048
#define NH 16
#define DK 64
#define DM 1024
#define BB 2
#define NROWS (BB * S_LEN)   // 4096
#define BHN (BB * NH)        // 32

typedef __attribute__((ext_vector_type(8))) short short8;          // MFMA A/B frag (8 bf16)
typedef __attribute__((ext_vector_type(8))) unsigned short u16x8;  // LDS/global store vector
typedef __attribute__((ext_vector_type(4))) float f32x4;           // MFMA C/D frag

#define LDS_W 72   // ushorts per LDS row for the attn kernels (64 data + 8 pad)

#define AS1C(p) ((const __attribute__((address_space(1))) void*)(p))
#define AS3(p)  ((__attribute__((address_space(3))) void*)(p))

__device__ __forceinline__ unsigned short f2bf(float x) {
  return __builtin_bit_cast(unsigned short, __float2bfloat16(x));  // RNE
}
__device__ __forceinline__ float bf2f(unsigned short u) {
  return __uint_as_float(((unsigned)u) << 16);
}

// ===================================================================
// Convert fp32 tensors into interleaved split-bf16 planes:
//   plane[row][chunk][0:32)  = hi bf16 of elements k = 32*chunk ..
//   plane[row][chunk][32:64) = lo bf16 (x - hi)
// Same byte count as the fp32 source. Row length must be %32 == 0.
// ===================================================================
struct ConvArgs {
  const float* src[8];
  unsigned short* dst[8];
  int n8[8];    // number of 8-element groups per tensor
};

__global__ __launch_bounds__(256)
void convert_all(ConvArgs a) {
  const int t = blockIdx.y;
  const float* __restrict__ s = a.src[t];
  unsigned short* __restrict__ d = a.dst[t];
  const int n8 = a.n8[t];
  for (int idx = blockIdx.x * 256 + threadIdx.x; idx < n8; idx += gridDim.x * 256) {
    const long f = (long)idx * 8;
    const float4 x0 = *(const float4*)(s + f);
    const float4 x1 = *(const float4*)(s + f + 4);
    const float xs[8] = {x0.x, x0.y, x0.z, x0.w, x1.x, x1.y, x1.z, x1.w};
    u16x8 hv, lv;
    #pragma unroll
    for (int j = 0; j < 8; ++j) {
      const unsigned short h = f2bf(xs[j]);
      hv[j] = h;
      lv[j] = f2bf(xs[j] - bf2f(h));
    }
    const long chunk = f >> 5;          // global 32-element chunk index
    const int pos = (int)(f & 31);      // 0, 8, 16, 24
    unsigned short* base = d + (chunk << 6) + pos;
    *(u16x8*)(base) = hv;
    *(u16x8*)(base + 32) = lv;
  }
}

// ===================================================================
// Plane GEMM: C = A(M x 1024) @ W(1024 x 1024)^T (+ bias), NT.
// A, W given as interleaved hi/lo bf16 planes. 128x128 tile, BK=64,
// 256 threads (4 waves 2x2), split-bf16 3-pass, fp32 accumulate.
// Staging: global_load_lds width 16, source-address XOR swizzle
// (slot ^= row&7 within each 8-slot chunk); ds_read applies same XOR.
// Double-buffered LDS (128 KiB), next tile staged before MFMA cluster.
// MODE 0: C fp32 row-major + bias (out projection)
// MODE 1: C fp32 (B,H,S,DK) layout + bias (q/k/v projections)
// ===================================================================
template<int MODE>
__global__ __launch_bounds__(256)
void plane_gemm(const unsigned short* __restrict__ Ap,
                const unsigned short* __restrict__ Bp,
                const float* __restrict__ bias, float* __restrict__ C)
{
  // tile per matrix per buffer: [128 rows][128 ushorts] = 32 KB
  __shared__ unsigned short sA[2][128 * 128];
  __shared__ unsigned short sB[2][128 * 128];
  const int tid = threadIdx.x;
  const int lane = tid & 63, w = tid >> 6;
  const int wr = w >> 1, wc = w & 1;
  const int lr = lane & 15, lg = lane >> 4;
  const int m0 = blockIdx.y * 128, n0 = blockIdx.x * 128;

  // staging geometry: waves 0,1 -> A halves; waves 2,3 -> B halves
  const unsigned short* gsrc = (w < 2) ? Ap : Bp;
  const int rowbase = ((w < 2) ? m0 : n0) + (w & 1) * 64;
  const int sl = lane & 15;   // dest slot 0..15 within 256B row group
  const int rl = lane >> 4;   // row 0..3 within a 1KB issue
  const int cb = sl >> 3;     // chunk bit (0: k 0..31, 1: k 32..63)
  const int s7 = sl & 7;      // slot within chunk

  f32x4 acc[4][4];
  #pragma unroll
  for (int m = 0; m < 4; ++m)
    #pragma unroll
    for (int n = 0; n < 4; ++n) acc[m][n] = (f32x4){0.f, 0.f, 0.f, 0.f};

  auto stage = [&](int kt, int buf) {
    unsigned short* lbase = ((w < 2) ? sA[buf] : sB[buf]) + (w & 1) * 8192;
    #pragma unroll
    for (int i = 0; i < 16; ++i) {
      const int r = i * 4 + rl;                 // row within this wave's 64-row half
      const size_t grow = (size_t)(rowbase + r);
      // inverse-swizzled source: dest slot s7 receives logical slot s7^(r&7)
      const size_t so = grow * 2048 + (size_t)(kt * 2 + cb) * 64 + ((s7 ^ (r & 7)) * 8);
      __builtin_amdgcn_global_load_lds(AS1C(gsrc + so), AS3(lbase + i * 512), 16, 0, 0);
    }
  };

  stage(0, 0);
  __syncthreads();
  int buf = 0;
  for (int kt = 0; kt < 16; ++kt) {
    #pragma unroll
    for (int kk = 0; kk < 2; ++kk) {
      short8 ah[4], al[4], bh[4], bl[4];
      #pragma unroll
      for (int m = 0; m < 4; ++m) {
        const int rr = wr * 64 + m * 16 + lr;
        const unsigned short* base = sA[buf] + rr * 128 + kk * 64;
        ah[m] = *(const short8*)(base + ((lg       ^ (rr & 7)) * 8));
        al[m] = *(const short8*)(base + (((lg + 4) ^ (rr & 7)) * 8));
      }
      #pragma unroll
      for (int n = 0; n < 4; ++n) {
        const int rr = wc * 64 + n * 16 + lr;
        const unsigned short* base = sB[buf] + rr * 128 + kk * 64;
        bh[n] = *(const short8*)(base + ((lg       ^ (rr & 7)) * 8));
        bl[n] = *(const short8*)(base + (((lg + 4) ^ (rr & 7)) * 8));
      }
      if (kk == 0 && kt < 15) stage(kt + 1, buf ^ 1);  // loads fly under the MFMAs
      #pragma unroll
      for (int m = 0; m < 4; ++m)
        #pragma unroll
        for (int n = 0; n < 4; ++n) {
          acc[m][n] = __builtin_amdgcn_mfma_f32_16x16x32_bf16(ah[m], bh[n], acc[m][n], 0, 0, 0);
          acc[m][n] = __builtin_amdgcn_mfma_f32_16x16x32_bf16(al[m], bh[n], acc[m][n], 0, 0, 0);
          acc[m][n] = __builtin_amdgcn_mfma_f32_16x16x32_bf16(ah[m], bl[n], acc[m][n], 0, 0, 0);
        }
    }
    __syncthreads();   // drains vmcnt (next tile staged) + lgkm (this tile's reads)
    buf ^= 1;
  }

  // epilogue: C fragment layout col = lane&15, row = (lane>>4)*4 + j
  #pragma unroll
  for (int n = 0; n < 4; ++n) {
    const int col = n0 + wc * 64 + n * 16 + lr;
    const float bb = bias[col];
    #pragma unroll
    for (int m = 0; m < 4; ++m) {
      const int rbase = m0 + wr * 64 + m * 16 + lg * 4;
      #pragma unroll
      for (int j = 0; j < 4; ++j) {
        const int row = rbase + j;
        const float o = acc[m][n][j] + bb;
        if (MODE == 0) {
          C[(size_t)row * DM + col] = o;
        } else {
          const int b = row >> 11, s = row & (S_LEN - 1);
          const int h = col >> 6, d = col & 63;
          C[(((size_t)(b * NH + h) * S_LEN + s) * DK + d)] = o;
        }
      }
    }
  }
}

// ===================================================================
// Stage a 128x64 fp32 tile (row stride ld) into hi/lo bf16 LDS planes
// (padded layout; used by the attention kernels only).
// ===================================================================
__device__ __forceinline__ void stage128x64(const float* __restrict__ base, int ld,
                                            unsigned short* sh, unsigned short* sl,
                                            int tid) {
  #pragma unroll
  for (int i = 0; i < 4; ++i) {
    const int f = tid + i * 256;
    const int r = f >> 3;
    const int c = (f & 7) * 8;
    const float* p = base + (size_t)r * ld + c;
    const float4 v0 = *(const float4*)(p);
    const float4 v1 = *(const float4*)(p + 4);
    const float xs[8] = {v0.x, v0.y, v0.z, v0.w, v1.x, v1.y, v1.z, v1.w};
    u16x8 hv, lv;
    #pragma unroll
    for (int j = 0; j < 8; ++j) {
      const unsigned short h = f2bf(xs[j]);
      hv[j] = h;
      lv[j] = f2bf(xs[j] - bf2f(h));
    }
    *(u16x8*)(sh + r * LDS_W + c) = hv;
    *(u16x8*)(sl + r * LDS_W + c) = lv;
  }
}

// ===================================================================
// Scores: attn_raw[bh,q,k] = (Qp[bh,q,:] . Kp[bh,k,:]) / 8, lower-
// triangular 128x128 blocks only. (Round-1 structure, K=64.)
// ===================================================================
__global__ __launch_bounds__(256)
void scores_kernel(const float* __restrict__ Qp, const float* __restrict__ Kp,
                   float* __restrict__ attn)
{
  __shared__ unsigned short As_h[128 * LDS_W], As_l[128 * LDS_W];
  __shared__ unsigned short Bs_h[128 * LDS_W], Bs_l[128 * LDS_W];
  const int tid = threadIdx.x;
  const int lane = tid & 63, wv = tid >> 6;
  const int wr = wv >> 1, wc = wv & 1;
  const int lr = lane & 15, lg = lane >> 4;
  const int r = blockIdx.x;
  int qb = 0;
  while ((qb + 1) * (qb + 2) / 2 <= r) qb++;
  const int kb = r - qb * (qb + 1) / 2;
  const int m0 = qb * 128, n0 = kb * 128;
  const float* Ab = Qp + ((size_t)blockIdx.y * S_LEN + m0) * DK;
  const float* Bb = Kp + ((size_t)blockIdx.y * S_LEN + n0) * DK;

  f32x4 acc[4][4];
  #pragma unroll
  for (int m = 0; m < 4; ++m)
    #pragma unroll
    for (int n = 0; n < 4; ++n) acc[m][n] = (f32x4){0.f, 0.f, 0.f, 0.f};

  stage128x64(Ab, DK, As_h, As_l, tid);
  stage128x64(Bb, DK, Bs_h, Bs_l, tid);
  __syncthreads();
  #pragma unroll
  for (int kk = 0; kk < 2; ++kk) {
    short8 ah[4], al[4], bh2[4], bl2[4];
    #pragma unroll
    for (int m = 0; m < 4; ++m) {
      const int off = (wr * 64 + m * 16 + lr) * LDS_W + kk * 32 + lg * 8;
      ah[m] = *(const short8*)(As_h + off);
      al[m] = *(const short8*)(As_l + off);
    }
    #pragma unroll
    for (int n = 0; n < 4; ++n) {
      const int off = (wc * 64 + n * 16 + lr) * LDS_W + kk * 32 + lg * 8;
      bh2[n] = *(const short8*)(Bs_h + off);
      bl2[n] = *(const short8*)(Bs_l + off);
    }
    #pragma unroll
    for (int m = 0; m < 4; ++m)
      #pragma unroll
      for (int n = 0; n < 4; ++n) {
        acc[m][n] = __builtin_amdgcn_mfma_f32_16x16x32_bf16(ah[m], bh2[n], acc[m][n], 0, 0, 0);
        acc[m][n] = __builtin_amdgcn_mfma_f32_16x16x32_bf16(al[m], bh2[n], acc[m][n], 0, 0, 0);
        acc[m][n] = __builtin_amdgcn_mfma_f32_16x16x32_bf16(ah[m], bl2[n], acc[m][n], 0, 0, 0);
      }
  }

  #pragma unroll
  for (int n = 0; n < 4; ++n) {
    const int col = n0 + wc * 64 + n * 16 + lr;
    #pragma unroll
    for (int m = 0; m < 4; ++m) {
      const int rbase = m0 + wr * 64 + m * 16 + lg * 4;
      #pragma unroll
      for (int j = 0; j < 4; ++j) {
        attn[((size_t)blockIdx.y * S_LEN + rbase + j) * S_LEN + col] = acc[m][n][j] * 0.125f;
      }
    }
  }
}

// ===================================================================
// Row softmax over attn, in place; writes zeros above the diagonal.
// ===================================================================
__global__ __launch_bounds__(256)
void softmax_kernel(float* __restrict__ attn)
{
  const int row = blockIdx.x;
  const int q = row & (S_LEN - 1);
  float* rowp = attn + (size_t)row * S_LEN;
  const int t = threadIdx.x;

  float vals[8];
  float m = -INFINITY;
  #pragma unroll
  for (int i = 0; i < 2; ++i) {
    const int c0 = (i * 256 + t) * 4;
    float4 x = make_float4(-INFINITY, -INFINITY, -INFINITY, -INFINITY);
    if (c0 <= q) x = *(const float4*)(rowp + c0);
    vals[i * 4 + 0] = (c0 + 0 <= q) ? x.x : -INFINITY;
    vals[i * 4 + 1] = (c0 + 1 <= q) ? x.y : -INFINITY;
    vals[i * 4 + 2] = (c0 + 2 <= q) ? x.z : -INFINITY;
    vals[i * 4 + 3] = (c0 + 3 <= q) ? x.w : -INFINITY;
    m = fmaxf(m, fmaxf(fmaxf(vals[i*4], vals[i*4+1]), fmaxf(vals[i*4+2], vals[i*4+3])));
  }
  #pragma unroll
  for (int off = 32; off > 0; off >>= 1)
    m = fmaxf(m, __shfl_xor(m, off));
  __shared__ float red[8];
  if ((t & 63) == 0) red[t >> 6] = m;
  __syncthreads();
  m = fmaxf(fmaxf(red[0], red[1]), fmaxf(red[2], red[3]));

  float s = 0.f;
  #pragma unroll
  for (int i = 0; i < 8; ++i) {
    const float e = __expf(vals[i] - m);
    vals[i] = e;
    s += e;
  }
  #pragma unroll
  for (int off = 32; off > 0; off >>= 1)
    s += __shfl_xor(s, off);
  if ((t & 63) == 0) red[4 + (t >> 6)] = s;
  __syncthreads();
  s = (red[4] + red[5]) + (red[6] + red[7]);
  const float inv = 1.0f / s;

  #pragma unroll
  for (int i = 0; i < 2; ++i) {
    const int c0 = (i * 256 + t) * 4;
    float4 o;
    o.x = vals[i * 4 + 0] * inv;
    o.y = vals[i * 4 + 1] * inv;
    o.z = vals[i * 4 + 2] * inv;
    o.w = vals[i * 4 + 3] * inv;
    *(float4*)(rowp + c0) = o;
  }
}

// ===================================================================
// PV: ctx[b,s,h*64+d] = sum_k attn[bh,s,k] * Vp[bh,k,d]  (round-1)
// ===================================================================
__global__ __launch_bounds__(256)
void pv_mfma(const float* __restrict__ attn, const float* __restrict__ Vp,
             float* __restrict__ ctx)
{
  __shared__ unsigned short As_h[128 * LDS_W], As_l[128 * LDS_W];
  __shared__ unsigned short Vs_h[64 * LDS_W],  Vs_l[64 * LDS_W];
  const int tid = threadIdx.x;
  const int lane = tid & 63, wv = tid >> 6;
  const int lr = lane & 15, lg = lane >> 4;
  const int bh = blockIdx.y;
  const int qb = 15 - blockIdx.x;
  const int q0 = qb * 128;
  const float* Ab = attn + ((size_t)bh * S_LEN + q0) * S_LEN;
  const float* Vb = Vp + (size_t)bh * S_LEN * DK;

  f32x4 acc[2][4];
  #pragma unroll
  for (int m = 0; m < 2; ++m)
    #pragma unroll
    for (int n = 0; n < 4; ++n) acc[m][n] = (f32x4){0.f, 0.f, 0.f, 0.f};

  const int nk = (q0 + 128) / 64;
  for (int kt = 0; kt < nk; ++kt) {
    stage128x64(Ab + kt * 64, S_LEN, As_h, As_l, tid);
    #pragma unroll
    for (int i = 0; i < 4; ++i) {
      const int g = tid + i * 256;
      const int kr = g >> 4;
      const int c4 = (g & 15) * 4;
      const float4 v = *(const float4*)(Vb + (size_t)(kt * 64 + kr) * DK + c4);
      const float xs[4] = {v.x, v.y, v.z, v.w};
      #pragma unroll
      for (int j = 0; j < 4; ++j) {
        const unsigned short h = f2bf(xs[j]);
        Vs_h[(c4 + j) * LDS_W + kr] = h;
        Vs_l[(c4 + j) * LDS_W + kr] = f2bf(xs[j] - bf2f(h));
      }
    }
    __syncthreads();
    #pragma unroll
    for (int kk = 0; kk < 2; ++kk) {
      short8 ah[2], al[2], bh2[4], bl2[4];
      #pragma unroll
      for (int m = 0; m < 2; ++m) {
        const int off = (wv * 32 + m * 16 + lr) * LDS_W + kk * 32 + lg * 8;
        ah[m] = *(const short8*)(As_h + off);
        al[m] = *(const short8*)(As_l + off);
      }
      #pragma unroll
      for (int n = 0; n < 4; ++n) {
        const int off = (n * 16 + lr) * LDS_W + kk * 32 + lg * 8;
        bh2[n] = *(const short8*)(Vs_h + off);
        bl2[n] = *(const short8*)(Vs_l + off);
      }
      #pragma unroll
      for (int m = 0; m < 2; ++m)
        #pragma unroll
        for (int n = 0; n < 4; ++n) {
          acc[m][n] = __builtin_amdgcn_mfma_f32_16x16x32_bf16(ah[m], bh2[n], acc[m][n], 0, 0, 0);
          acc[m][n] = __builtin_amdgcn_mfma_f32_16x16x32_bf16(al[m], bh2[n], acc[m][n], 0, 0, 0);
          acc[m][n] = __builtin_amdgcn_mfma_f32_16x16x32_bf16(ah[m], bl2[n], acc[m][n], 0, 0, 0);
        }
    }
    __syncthreads();
  }

  const int b = bh >> 4, h = bh & 15;
  #pragma unroll
  for (int n = 0; n < 4; ++n) {
    const int d = n * 16 + lr;
    #pragma unroll
    for (int m = 0; m < 2; ++m) {
      #pragma unroll
      for (int j = 0; j < 4; ++j) {
        const int s = q0 + wv * 32 + m * 16 + lg * 4 + j;
        ctx[((size_t)b * S_LEN + s) * DM + h * DK + d] = acc[m][n][j];
      }
    }
  }
}

// ===================================================================
extern "C" void kernel_launch(void* const* d_in, const int* in_sizes, int n_in,
                              void* d_out, int out_size, void* d_ws, size_t ws_size,
                              hipStream_t stream) {
  const float* q   = (const float*)d_in[0];
  const float* k   = (const float*)d_in[1];
  const float* v   = (const float*)d_in[2];
  // d_in[3] = causal mask -> analytic, never read
  const float* w_q = (const float*)d_in[4];
  const float* b_q = (const float*)d_in[5];
  const float* w_k = (const float*)d_in[6];
  const float* b_k = (const float*)d_in[7];
  const float* w_v = (const float*)d_in[8];
  const float* b_v = (const float*)d_in[9];
  const float* w_o = (const float*)d_in[10];
  const float* b_o = (const float*)d_in[11];

  float* out  = (float*)d_out;                      // (B, S, DM)
  float* attn = out + (size_t)NROWS * DM;           // (B, H, S, S)

  const size_t MB = 1024 * 1024;
  char* wsb = (char*)d_ws;                          // uses 144 MB of d_ws
  unsigned short* qP  = (unsigned short*)(wsb + 0 * MB);    // 16 MB each
  unsigned short* kP  = (unsigned short*)(wsb + 16 * MB);
  unsigned short* vP  = (unsigned short*)(wsb + 32 * MB);
  unsigned short* wqP = (unsigned short*)(wsb + 48 * MB);   // 4 MB each
  unsigned short* wkP = (unsigned short*)(wsb + 52 * MB);
  unsigned short* wvP = (unsigned short*)(wsb + 56 * MB);
  unsigned short* woP = (unsigned short*)(wsb + 60 * MB);
  float* Qp  = (float*)(wsb + 64 * MB);             // (B,H,S,DK) fp32
  float* Kp  = (float*)(wsb + 80 * MB);
  float* Vp  = (float*)(wsb + 96 * MB);
  float* ctx = (float*)(wsb + 112 * MB);            // (B,S,DM) fp32
  unsigned short* cP = (unsigned short*)(wsb + 128 * MB);   // ctx planes, 16 MB

  // ---- convert inputs + weights to split-bf16 planes ----
  ConvArgs ca = {};
  ca.src[0] = q;   ca.dst[0] = qP;  ca.n8[0] = NROWS * DM / 8;
  ca.src[1] = k;   ca.dst[1] = kP;  ca.n8[1] = NROWS * DM / 8;
  ca.src[2] = v;   ca.dst[2] = vP;  ca.n8[2] = NROWS * DM / 8;
  ca.src[3] = w_q; ca.dst[3] = wqP; ca.n8[3] = DM * DM / 8;
  ca.src[4] = w_k; ca.dst[4] = wkP; ca.n8[4] = DM * DM / 8;
  ca.src[5] = w_v; ca.dst[5] = wvP; ca.n8[5] = DM * DM / 8;
  ca.src[6] = w_o; ca.dst[6] = woP; ca.n8[6] = DM * DM / 8;
  ca.src[7] = q;   ca.dst[7] = qP;  ca.n8[7] = 0;
  convert_all<<<dim3(2048, 7), 256, 0, stream>>>(ca);

  // ---- projections ----
  const dim3 gproj(DM / 128, NROWS / 128);          // (8, 32) = 256 blocks
  plane_gemm<1><<<gproj, 256, 0, stream>>>(qP, wqP, b_q, Qp);
  plane_gemm<1><<<gproj, 256, 0, stream>>>(kP, wkP, b_k, Kp);
  plane_gemm<1><<<gproj, 256, 0, stream>>>(vP, wvP, b_v, Vp);

  // ---- attention ----
  scores_kernel<<<dim3(136, BHN), 256, 0, stream>>>(Qp, Kp, attn);
  softmax_kernel<<<dim3(BB * NH * S_LEN), 256, 0, stream>>>(attn);
  pv_mfma<<<dim3(16, BHN), 256, 0, stream>>>(attn, Vp, ctx);

  // ---- out projection ----
  ConvArgs cc = {};
  cc.src[0] = ctx; cc.dst[0] = cP; cc.n8[0] = NROWS * DM / 8;
  for (int i = 1; i < 8; ++i) { cc.src[i] = ctx; cc.dst[i] = cP; cc.n8[i] = 0; }
  convert_all<<<dim3(2048, 1), 256, 0, stream>>>(cc);
  plane_gemm<0><<<gproj, 256, 0, stream>>>(cP, woP, b_o, out);
}

// Round 5
// 938.583 us; speedup vs baseline: 1.6826x; 1.1220x over previous
//
#include <hip/hip_runtime.h>
#include <hip/hip_bf16.h>
#include <math.h>

#define S_LEN 2048
#define NH 16
#define DK 64
#define DM 1024
#define BB 2
#define NROWS (BB * S_LEN)   // 4096
#define BHN (BB * NH)        // 32

typedef __attribute__((ext_vector_type(8))) short short8;          // MFMA A/B frag (8 bf16)
typedef __attribute__((ext_vector_type(8))) unsigned short u16x8;  // 16B vector
typedef __attribute__((ext_vector_type(4))) float f32x4;           // MFMA C/D frag

#define AS1C(p) ((const __attribute__((address_space(1))) void*)(p))
#define AS3(p)  ((__attribute__((address_space(3))) void*)(p))
// bank swizzle: 16B-slot index s (0..15) XOR'd with row&7 — baked into global
// plane layouts so global_load_lds copies verbatim; ds_reads apply same XOR.
#define SW(s, r) ((s) ^ ((r) & 7))

__device__ __forceinline__ unsigned short f2bf(float x) {
  return __builtin_bit_cast(unsigned short, __float2bfloat16(x));  // RNE
}
__device__ __forceinline__ float bf2f(unsigned short u) {
  return __uint_as_float(((unsigned)u) << 16);
}

// ===================================================================
// convert_all: fp32 -> interleaved split-bf16 planes, UNswizzled
// (consumed by plane_gemm which swizzles at its own gll source).
// plane[row][chunk][0:32)=hi, [32:64)=lo, chunk = 32 elems.
// ===================================================================
struct ConvArgs {
  const float* src[8];
  unsigned short* dst[8];
  int n8[8];
};

__global__ __launch_bounds__(256)
void convert_all(ConvArgs a) {
  const int t = blockIdx.y;
  const float* __restrict__ s = a.src[t];
  unsigned short* __restrict__ d = a.dst[t];
  const int n8 = a.n8[t];
  for (int idx = blockIdx.x * 256 + threadIdx.x; idx < n8; idx += gridDim.x * 256) {
    const long f = (long)idx * 8;
    const float4 x0 = *(const float4*)(s + f);
    const float4 x1 = *(const float4*)(s + f + 4);
    const float xs[8] = {x0.x, x0.y, x0.z, x0.w, x1.x, x1.y, x1.z, x1.w};
    u16x8 hv, lv;
    #pragma unroll
    for (int j = 0; j < 8; ++j) {
      const unsigned short h = f2bf(xs[j]);
      hv[j] = h;
      lv[j] = f2bf(xs[j] - bf2f(h));
    }
    const long chunk = f >> 5;
    const int pos = (int)(f & 31);
    unsigned short* base = d + (chunk << 6) + pos;
    *(u16x8*)(base) = hv;
    *(u16x8*)(base + 32) = lv;
  }
}

// ===================================================================
// conv_qk: fp32 (rows of 64) -> split-bf16 planes WITH baked bank
// swizzle. Row = 128 ushorts = 16 slots of 16B; slot s -> s^(row&7).
// ===================================================================
__global__ __launch_bounds__(256)
void conv_qk(const float* __restrict__ src, unsigned short* __restrict__ dst, int n8) {
  for (int idx = blockIdx.x * 256 + threadIdx.x; idx < n8; idx += gridDim.x * 256) {
    const long g = (long)idx * 8;
    const int row = (int)(g >> 6);
    const int k0 = (int)(g & 63);          // 0,8,..,56
    const float4 x0 = *(const float4*)(src + g);
    const float4 x1 = *(const float4*)(src + g + 4);
    const float xs[8] = {x0.x, x0.y, x0.z, x0.w, x1.x, x1.y, x1.z, x1.w};
    u16x8 hv, lv;
    #pragma unroll
    for (int j = 0; j < 8; ++j) {
      const unsigned short h = f2bf(xs[j]);
      hv[j] = h;
      lv[j] = f2bf(xs[j] - bf2f(h));
    }
    const int c = k0 >> 5, sq = (k0 & 31) >> 3;
    const int s0 = c * 8 + sq;             // hi slot; lo slot = s0+4
    unsigned short* base = dst + (size_t)row * 128;
    *(u16x8*)(base + SW(s0, row) * 8) = hv;
    *(u16x8*)(base + SW(s0 + 4, row) * 8) = lv;
  }
}

// ===================================================================
// conv_vt: Vp (bh, k, d) fp32 -> Vt tiles (bh, kblk, d<64>, 128 ush)
// = V^T split-bf16 planes, swizzled by d&7. Tile = 16 KB contiguous.
// ===================================================================
__global__ __launch_bounds__(256)
void conv_vt(const float* __restrict__ Vp, unsigned short* __restrict__ Vt) {
  __shared__ float T[64][65];
  const int kblk = blockIdx.x, bh = blockIdx.y;
  const int tid = threadIdx.x;
  const float* src = Vp + ((size_t)bh * S_LEN + kblk * 64) * DK;
  #pragma unroll
  for (int i = 0; i < 4; ++i) {
    const int idx = tid + i * 256;
    const int kr = idx >> 4, dc = (idx & 15) * 4;
    const float4 v = *(const float4*)(src + (size_t)kr * DK + dc);
    T[kr][dc] = v.x; T[kr][dc + 1] = v.y; T[kr][dc + 2] = v.z; T[kr][dc + 3] = v.w;
  }
  __syncthreads();
  unsigned short* dtile = Vt + (size_t)(bh * 32 + kblk) * 64 * 128;
  #pragma unroll
  for (int i = 0; i < 2; ++i) {
    const int u = tid + i * 256;
    const int d = u >> 3, ko = (u & 7) * 8;
    float xs[8];
    #pragma unroll
    for (int j = 0; j < 8; ++j) xs[j] = T[ko + j][d];
    u16x8 hv, lv;
    #pragma unroll
    for (int j = 0; j < 8; ++j) {
      const unsigned short h = f2bf(xs[j]);
      hv[j] = h;
      lv[j] = f2bf(xs[j] - bf2f(h));
    }
    const int c = ko >> 5, sq = (ko & 31) >> 3;
    const int s0 = c * 8 + sq;
    unsigned short* base = dtile + d * 128;
    *(u16x8*)(base + SW(s0, d) * 8) = hv;
    *(u16x8*)(base + SW(s0 + 4, d) * 8) = lv;
  }
}

// ===================================================================
// zero_upper: attn cols strictly above the diagonal 64-block = 0.
// ===================================================================
__global__ __launch_bounds__(256)
void zero_upper(float* __restrict__ attn) {
  const int qt = blockIdx.x;        // 0..30
  const int bh = blockIdx.y;
  const int c0 = (qt + 1) * 64;
  float* base = attn + ((size_t)bh * S_LEN + qt * 64) * S_LEN;
  const float4 z = {0.f, 0.f, 0.f, 0.f};
  for (int r = 0; r < 64; ++r)
    for (int c = c0 + threadIdx.x * 4; c < S_LEN; c += 1024)
      *(float4*)(base + (size_t)r * S_LEN + c) = z;
}

// ===================================================================
// plane_gemm: C = A @ W^T + bias, NT, 128x128 tile, BK=64,
// gll staging with source swizzle, dbuf LDS. (Validated in round 3.)
// ===================================================================
template<int MODE>
__global__ __launch_bounds__(256)
void plane_gemm(const unsigned short* __restrict__ Ap,
                const unsigned short* __restrict__ Bp,
                const float* __restrict__ bias, float* __restrict__ C)
{
  __shared__ unsigned short sA[2][128 * 128];
  __shared__ unsigned short sB[2][128 * 128];
  const int tid = threadIdx.x;
  const int lane = tid & 63, w = tid >> 6;
  const int wr = w >> 1, wc = w & 1;
  const int lr = lane & 15, lg = lane >> 4;
  const int m0 = blockIdx.y * 128, n0 = blockIdx.x * 128;

  const unsigned short* gsrc = (w < 2) ? Ap : Bp;
  const int rowbase = ((w < 2) ? m0 : n0) + (w & 1) * 64;
  const int sl = lane & 15;
  const int rl = lane >> 4;
  const int cb = sl >> 3;
  const int s7 = sl & 7;

  f32x4 acc[4][4];
  #pragma unroll
  for (int m = 0; m < 4; ++m)
    #pragma unroll
    for (int n = 0; n < 4; ++n) acc[m][n] = (f32x4){0.f, 0.f, 0.f, 0.f};

  auto stage = [&](int kt, int buf) {
    unsigned short* lbase = ((w < 2) ? sA[buf] : sB[buf]) + (w & 1) * 8192;
    #pragma unroll
    for (int i = 0; i < 16; ++i) {
      const int r = i * 4 + rl;
      const size_t grow = (size_t)(rowbase + r);
      const size_t so = grow * 2048 + (size_t)(kt * 2 + cb) * 64 + ((s7 ^ (r & 7)) * 8);
      __builtin_amdgcn_global_load_lds(AS1C(gsrc + so), AS3(lbase + i * 512), 16, 0, 0);
    }
  };

  stage(0, 0);
  __syncthreads();
  int buf = 0;
  for (int kt = 0; kt < 16; ++kt) {
    #pragma unroll
    for (int kk = 0; kk < 2; ++kk) {
      short8 ah[4], al[4], bh[4], bl[4];
      #pragma unroll
      for (int m = 0; m < 4; ++m) {
        const int rr = wr * 64 + m * 16 + lr;
        const unsigned short* base = sA[buf] + rr * 128 + kk * 64;
        ah[m] = *(const short8*)(base + ((lg       ^ (rr & 7)) * 8));
        al[m] = *(const short8*)(base + (((lg + 4) ^ (rr & 7)) * 8));
      }
      #pragma unroll
      for (int n = 0; n < 4; ++n) {
        const int rr = wc * 64 + n * 16 + lr;
        const unsigned short* base = sB[buf] + rr * 128 + kk * 64;
        bh[n] = *(const short8*)(base + ((lg       ^ (rr & 7)) * 8));
        bl[n] = *(const short8*)(base + (((lg + 4) ^ (rr & 7)) * 8));
      }
      if (kk == 0 && kt < 15) stage(kt + 1, buf ^ 1);
      #pragma unroll
      for (int m = 0; m < 4; ++m)
        #pragma unroll
        for (int n = 0; n < 4; ++n) {
          acc[m][n] = __builtin_amdgcn_mfma_f32_16x16x32_bf16(ah[m], bh[n], acc[m][n], 0, 0, 0);
          acc[m][n] = __builtin_amdgcn_mfma_f32_16x16x32_bf16(al[m], bh[n], acc[m][n], 0, 0, 0);
          acc[m][n] = __builtin_amdgcn_mfma_f32_16x16x32_bf16(ah[m], bl[n], acc[m][n], 0, 0, 0);
        }
    }
    __syncthreads();
    buf ^= 1;
  }

  #pragma unroll
  for (int n = 0; n < 4; ++n) {
    const int col = n0 + wc * 64 + n * 16 + lr;
    const float bb = bias[col];
    #pragma unroll
    for (int m = 0; m < 4; ++m) {
      const int rbase = m0 + wr * 64 + m * 16 + lg * 4;
      #pragma unroll
      for (int j = 0; j < 4; ++j) {
        const int row = rbase + j;
        const float o = acc[m][n][j] + bb;
        if (MODE == 0) {
          C[(size_t)row * DM + col] = o;
        } else {
          const int b = row >> 11, s = row & (S_LEN - 1);
          const int h = col >> 6, d = col & 63;
          C[(((size_t)(b * NH + h) * S_LEN + s) * DK + d)] = o;
        }
      }
    }
  }
}

// ===================================================================
// fused_attn: per (bh, 64-row q-tile): two-pass flash.
// Pass 1: stream K-tiles, S = Q·K^T/8 (3-pass split-bf16 MFMA),
//         online row max m / sum l (no stores).
// Pass 2: recompute S (bit-identical), P = exp(S-m)/l, write attn,
//         P->LDS split-bf16, PV MFMA accumulate, write ctx.
// All staging via global_load_lds from pre-swizzled planes.
// ===================================================================
__global__ __launch_bounds__(256, 2)
void fused_attn(const unsigned short* __restrict__ Qpl,
                const unsigned short* __restrict__ Kpl,
                const unsigned short* __restrict__ Vtpl,
                float* __restrict__ attn, float* __restrict__ ctx)
{
  __shared__ unsigned short Ks[2][64 * 128];   // 32 KB (dbuf)
  __shared__ unsigned short Vs[64 * 128];      // 16 KB
  __shared__ unsigned short PQs[64 * 128];     // 16 KB (Q prologue, then P)
  __shared__ float m_l[64], l_l[64], redm[2][64], reds[2][64];

  const int tid = threadIdx.x;
  const int lane = tid & 63, w = tid >> 6;
  const int wr = w >> 1, wc = w & 1;
  const int lr = lane & 15, lg = lane >> 4;

  // XCD-pinned swizzle: 4 bh per XCD (1 MB K+V planes -> L2-resident);
  // largest q-tiles dispatched first.
  const int wg = blockIdx.x;
  const int xcd = wg & 7, ii = wg >> 3;
  const int bh = xcd * 4 + (ii & 3);
  const int qt = 31 - (ii >> 2);
  const int q0 = qt * 64;
  const int nk = qt + 1;

  const unsigned short* Qb = Qpl + ((size_t)bh * S_LEN + q0) * 128;
  const unsigned short* Kb = Kpl + (size_t)bh * S_LEN * 128;
  const unsigned short* Vb = Vtpl + (size_t)bh * 32 * 64 * 128;

  // stage 64 rows x 128 ushorts (16 KB) linearly; src is pre-swizzled.
  auto stage64 = [&](const unsigned short* srcRow0, unsigned short* dst) {
    #pragma unroll
    for (int j = 0; j < 4; ++j) {
      const int rb = w * 16 + j * 4;
      const unsigned short* src = srcRow0 + (size_t)(rb + (lane >> 4)) * 128 + (lane & 15) * 8;
      __builtin_amdgcn_global_load_lds(AS1C(src), AS3(dst + rb * 128), 16, 0, 0);
    }
  };

  stage64(Qb, PQs);
  stage64(Kb, Ks[0]);
  if (tid < 64) { m_l[tid] = -INFINITY; l_l[tid] = 0.f; }
  __syncthreads();

  // hoist Q fragments (reused by both passes)
  short8 qh[2][2], ql[2][2];
  #pragma unroll
  for (int mf = 0; mf < 2; ++mf) {
    const int row = wr * 32 + mf * 16 + lr;
    const unsigned short* base = PQs + row * 128;
    #pragma unroll
    for (int kk = 0; kk < 2; ++kk) {
      qh[mf][kk] = *(const short8*)(base + SW(kk * 8 + lg, row) * 8);
      ql[mf][kk] = *(const short8*)(base + SW(kk * 8 + 4 + lg, row) * 8);
    }
  }

  f32x4 sacc[2][2];
  auto compute_S = [&](const unsigned short* K, int kt) {
    #pragma unroll
    for (int mf = 0; mf < 2; ++mf)
      #pragma unroll
      for (int nf = 0; nf < 2; ++nf) sacc[mf][nf] = (f32x4){0.f, 0.f, 0.f, 0.f};
    #pragma unroll
    for (int kk = 0; kk < 2; ++kk) {
      short8 kh[2], kl[2];
      #pragma unroll
      for (int nf = 0; nf < 2; ++nf) {
        const int krow = wc * 32 + nf * 16 + lr;
        const unsigned short* base = K + krow * 128;
        kh[nf] = *(const short8*)(base + SW(kk * 8 + lg, krow) * 8);
        kl[nf] = *(const short8*)(base + SW(kk * 8 + 4 + lg, krow) * 8);
      }
      #pragma unroll
      for (int mf = 0; mf < 2; ++mf)
        #pragma unroll
        for (int nf = 0; nf < 2; ++nf) {
          sacc[mf][nf] = __builtin_amdgcn_mfma_f32_16x16x32_bf16(qh[mf][kk], kh[nf], sacc[mf][nf], 0, 0, 0);
          sacc[mf][nf] = __builtin_amdgcn_mfma_f32_16x16x32_bf16(ql[mf][kk], kh[nf], sacc[mf][nf], 0, 0, 0);
          sacc[mf][nf] = __builtin_amdgcn_mfma_f32_16x16x32_bf16(qh[mf][kk], kl[nf], sacc[mf][nf], 0, 0, 0);
        }
    }
    #pragma unroll
    for (int mf = 0; mf < 2; ++mf)
      #pragma unroll
      for (int nf = 0; nf < 2; ++nf)
        #pragma unroll
        for (int j = 0; j < 4; ++j) {
          float v = sacc[mf][nf][j] * 0.125f;
          if (kt == qt) {   // diagonal block: mask cols > row
            const int lcol = wc * 32 + nf * 16 + lr;
            const int lrow = wr * 32 + mf * 16 + lg * 4 + j;
            if (lcol > lrow) v = -INFINITY;
          }
          sacc[mf][nf][j] = v;
        }
  };

  // -------- pass 1: stats --------
  int buf = 0;
  for (int kt = 0; kt < nk; ++kt) {
    stage64(Kb + (size_t)((kt + 1 < nk) ? (kt + 1) : 0) * 64 * 128, Ks[buf ^ 1]);
    compute_S(Ks[buf], kt);

    float pm[2][4];
    #pragma unroll
    for (int mf = 0; mf < 2; ++mf)
      #pragma unroll
      for (int j = 0; j < 4; ++j) {
        float v = fmaxf(sacc[mf][0][j], sacc[mf][1][j]);
        #pragma unroll
        for (int off = 1; off < 16; off <<= 1) v = fmaxf(v, __shfl_xor(v, off));
        pm[mf][j] = v;
      }
    if (lr == 0) {
      #pragma unroll
      for (int mf = 0; mf < 2; ++mf)
        #pragma unroll
        for (int j = 0; j < 4; ++j)
          redm[wc][wr * 32 + mf * 16 + lg * 4 + j] = pm[mf][j];
    }
    __syncthreads();   // B1

    float nm_[2][4], mo_[2][4], es_[2][4];
    #pragma unroll
    for (int mf = 0; mf < 2; ++mf)
      #pragma unroll
      for (int j = 0; j < 4; ++j) {
        const int row = wr * 32 + mf * 16 + lg * 4 + j;
        const float tm = fmaxf(redm[0][row], redm[1][row]);
        mo_[mf][j] = m_l[row];
        nm_[mf][j] = fmaxf(mo_[mf][j], tm);
        float e = __expf(sacc[mf][0][j] - nm_[mf][j]) + __expf(sacc[mf][1][j] - nm_[mf][j]);
        #pragma unroll
        for (int off = 1; off < 16; off <<= 1) e += __shfl_xor(e, off);
        es_[mf][j] = e;
      }
    if (lr == 0) {
      #pragma unroll
      for (int mf = 0; mf < 2; ++mf)
        #pragma unroll
        for (int j = 0; j < 4; ++j)
          reds[wc][wr * 32 + mf * 16 + lg * 4 + j] = es_[mf][j];
    }
    __syncthreads();   // B2
    if (wc == 0 && lr == 0) {
      #pragma unroll
      for (int mf = 0; mf < 2; ++mf)
        #pragma unroll
        for (int j = 0; j < 4; ++j) {
          const int row = wr * 32 + mf * 16 + lg * 4 + j;
          l_l[row] = l_l[row] * __expf(mo_[mf][j] - nm_[mf][j]) + reds[0][row] + reds[1][row];
          m_l[row] = nm_[mf][j];
        }
    }
    __syncthreads();   // B3 (also: staged K ready)
    buf ^= 1;
  }

  // final row stats -> registers
  float rm[2][4], rinv[2][4];
  #pragma unroll
  for (int mf = 0; mf < 2; ++mf)
    #pragma unroll
    for (int j = 0; j < 4; ++j) {
      const int row = wr * 32 + mf * 16 + lg * 4 + j;
      rm[mf][j] = m_l[row];
      rinv[mf][j] = 1.0f / l_l[row];
    }

  // -------- pass 2: P write + PV --------
  f32x4 acc_o[2][2];
  #pragma unroll
  for (int mf = 0; mf < 2; ++mf)
    #pragma unroll
    for (int nf = 0; nf < 2; ++nf) acc_o[mf][nf] = (f32x4){0.f, 0.f, 0.f, 0.f};

  for (int kt = 0; kt < nk; ++kt) {
    stage64(Vb + (size_t)kt * 64 * 128, Vs);
    if (kt + 1 < nk) stage64(Kb + (size_t)(kt + 1) * 64 * 128, Ks[buf ^ 1]);
    compute_S(Ks[buf], kt);

    // P = exp(S - m) / l ; write attn + LDS split-bf16 planes
    #pragma unroll
    for (int mf = 0; mf < 2; ++mf)
      #pragma unroll
      for (int nf = 0; nf < 2; ++nf)
        #pragma unroll
        for (int j = 0; j < 4; ++j) {
          const int lrow = wr * 32 + mf * 16 + lg * 4 + j;
          const int lcol = wc * 32 + nf * 16 + lr;
          const float p = __expf(sacc[mf][nf][j] - rm[mf][j]) * rinv[mf][j];
          attn[((size_t)bh * S_LEN + q0 + lrow) * S_LEN + kt * 64 + lcol] = p;
          const unsigned short h = f2bf(p);
          const unsigned short lo = f2bf(p - bf2f(h));
          const int u = ((lcol >> 5) << 6) + (lcol & 31);
          const int s0 = u >> 3, pos = u & 7;
          PQs[lrow * 128 + SW(s0, lrow) * 8 + pos] = h;
          PQs[lrow * 128 + SW(s0 + 4, lrow) * 8 + pos] = lo;
        }
    __syncthreads();   // β1: P + V visible, next K loaded

    #pragma unroll
    for (int kk = 0; kk < 2; ++kk) {
      short8 ph[2], pl[2], vh[2], vl[2];
      #pragma unroll
      for (int mf = 0; mf < 2; ++mf) {
        const int row = wr * 32 + mf * 16 + lr;
        const unsigned short* base = PQs + row * 128;
        ph[mf] = *(const short8*)(base + SW(kk * 8 + lg, row) * 8);
        pl[mf] = *(const short8*)(base + SW(kk * 8 + 4 + lg, row) * 8);
      }
      #pragma unroll
      for (int nf = 0; nf < 2; ++nf) {
        const int d = wc * 32 + nf * 16 + lr;
        const unsigned short* base = Vs + d * 128;
        vh[nf] = *(const short8*)(base + SW(kk * 8 + lg, d) * 8);
        vl[nf] = *(const short8*)(base + SW(kk * 8 + 4 + lg, d) * 8);
      }
      #pragma unroll
      for (int mf = 0; mf < 2; ++mf)
        #pragma unroll
        for (int nf = 0; nf < 2; ++nf) {
          acc_o[mf][nf] = __builtin_amdgcn_mfma_f32_16x16x32_bf16(ph[mf], vh[nf], acc_o[mf][nf], 0, 0, 0);
          acc_o[mf][nf] = __builtin_amdgcn_mfma_f32_16x16x32_bf16(pl[mf], vh[nf], acc_o[mf][nf], 0, 0, 0);
          acc_o[mf][nf] = __builtin_amdgcn_mfma_f32_16x16x32_bf16(ph[mf], vl[nf], acc_o[mf][nf], 0, 0, 0);
        }
    }
    __syncthreads();   // β2: safe to overwrite Vs/PQs next iter
    buf ^= 1;
  }

  // epilogue: ctx (B, S, DM) fp32
  const int b = bh >> 4, h = bh & 15;
  #pragma unroll
  for (int mf = 0; mf < 2; ++mf)
    #pragma unroll
    for (int nf = 0; nf < 2; ++nf)
      #pragma unroll
      for (int j = 0; j < 4; ++j) {
        const int s = q0 + wr * 32 + mf * 16 + lg * 4 + j;
        const int d = wc * 32 + nf * 16 + lr;
        ctx[((size_t)b * S_LEN + s) * DM + h * DK + d] = acc_o[mf][nf][j];
      }
}

// ===================================================================
extern "C" void kernel_launch(void* const* d_in, const int* in_sizes, int n_in,
                              void* d_out, int out_size, void* d_ws, size_t ws_size,
                              hipStream_t stream) {
  const float* q   = (const float*)d_in[0];
  const float* k   = (const float*)d_in[1];
  const float* v   = (const float*)d_in[2];
  // d_in[3] = causal mask -> analytic, never read
  const float* w_q = (const float*)d_in[4];
  const float* b_q = (const float*)d_in[5];
  const float* w_k = (const float*)d_in[6];
  const float* b_k = (const float*)d_in[7];
  const float* w_v = (const float*)d_in[8];
  const float* b_v = (const float*)d_in[9];
  const float* w_o = (const float*)d_in[10];
  const float* b_o = (const float*)d_in[11];

  float* out  = (float*)d_out;                      // (B, S, DM)
  float* attn = out + (size_t)NROWS * DM;           // (B, H, S, S)

  const size_t MB = 1024 * 1024;
  char* wsb = (char*)d_ws;                          // uses 192 MB of d_ws
  unsigned short* qP   = (unsigned short*)(wsb + 0 * MB);
  unsigned short* kP   = (unsigned short*)(wsb + 16 * MB);
  unsigned short* vP   = (unsigned short*)(wsb + 32 * MB);
  unsigned short* wqP  = (unsigned short*)(wsb + 48 * MB);
  unsigned short* wkP  = (unsigned short*)(wsb + 52 * MB);
  unsigned short* wvP  = (unsigned short*)(wsb + 56 * MB);
  unsigned short* woP  = (unsigned short*)(wsb + 60 * MB);
  float* Qp  = (float*)(wsb + 64 * MB);             // (B,H,S,DK) fp32
  float* Kp  = (float*)(wsb + 80 * MB);
  float* Vp  = (float*)(wsb + 96 * MB);
  float* ctx = (float*)(wsb + 112 * MB);            // (B,S,DM) fp32
  unsigned short* cP   = (unsigned short*)(wsb + 128 * MB);
  unsigned short* Qpl  = (unsigned short*)(wsb + 144 * MB);  // swizzled planes
  unsigned short* Kpl  = (unsigned short*)(wsb + 160 * MB);
  unsigned short* Vtpl = (unsigned short*)(wsb + 176 * MB);

  // ---- convert inputs + weights to (unswizzled) planes ----
  ConvArgs ca = {};
  ca.src[0] = q;   ca.dst[0] = qP;  ca.n8[0] = NROWS * DM / 8;
  ca.src[1] = k;   ca.dst[1] = kP;  ca.n8[1] = NROWS * DM / 8;
  ca.src[2] = v;   ca.dst[2] = vP;  ca.n8[2] = NROWS * DM / 8;
  ca.src[3] = w_q; ca.dst[3] = wqP; ca.n8[3] = DM * DM / 8;
  ca.src[4] = w_k; ca.dst[4] = wkP; ca.n8[4] = DM * DM / 8;
  ca.src[5] = w_v; ca.dst[5] = wvP; ca.n8[5] = DM * DM / 8;
  ca.src[6] = w_o; ca.dst[6] = woP; ca.n8[6] = DM * DM / 8;
  ca.src[7] = q;   ca.dst[7] = qP;  ca.n8[7] = 0;
  convert_all<<<dim3(2048, 7), 256, 0, stream>>>(ca);

  // ---- projections ----
  const dim3 gproj(DM / 128, NROWS / 128);
  plane_gemm<1><<<gproj, 256, 0, stream>>>(qP, wqP, b_q, Qp);
  plane_gemm<1><<<gproj, 256, 0, stream>>>(kP, wkP, b_k, Kp);
  plane_gemm<1><<<gproj, 256, 0, stream>>>(vP, wvP, b_v, Vp);

  // ---- attention prep: swizzled split-bf16 planes ----
  const int nqk8 = BHN * S_LEN * DK / 8;            // 524288 groups
  conv_qk<<<2048, 256, 0, stream>>>(Qp, Qpl, nqk8);
  conv_qk<<<2048, 256, 0, stream>>>(Kp, Kpl, nqk8);
  conv_vt<<<dim3(32, BHN), 256, 0, stream>>>(Vp, Vtpl);
  zero_upper<<<dim3(31, BHN), 256, 0, stream>>>(attn);

  // ---- fused attention ----
  fused_attn<<<dim3(1024), 256, 0, stream>>>(Qpl, Kpl, Vtpl, attn, ctx);

  // ---- out projection ----
  ConvArgs cc = {};
  cc.src[0] = ctx; cc.dst[0] = cP; cc.n8[0] = NROWS * DM / 8;
  for (int i = 1; i < 8; ++i) { cc.src[i] = ctx; cc.dst[i] = cP; cc.n8[i] = 0; }
  convert_all<<<dim3(2048, 1), 256, 0, stream>>>(cc);
  plane_gemm<0><<<gproj, 256, 0, stream>>>(cP, woP, b_o, out);
}